// Round 3
// baseline (270.371 us; speedup 1.0000x reference)
//
#include <hip/hip_runtime.h>
#include <hip/hip_bf16.h>

// Problem constants (from reference)
#define BATCH 2
#define SEQ   2048
#define DMODEL 1024
#define NHEAD 16
#define DK    64
#define MTOK  (BATCH * SEQ)      // 4096 token rows

typedef __attribute__((ext_vector_type(8))) short bf16x8;   // 8 bf16 in 4 VGPRs
typedef __attribute__((ext_vector_type(4))) float f32x4;    // MFMA 16x16 accumulator

// float -> bf16 bits, round-to-nearest-even
__device__ __forceinline__ unsigned short f2bf(float x) {
    unsigned u = __float_as_uint(x);
    u = (u + 0x7FFFu + ((u >> 16) & 1u)) >> 16;
    return (unsigned short)u;
}

__device__ __forceinline__ void store_out(float* p, float v)          { *p = v; }
__device__ __forceinline__ void store_out(unsigned short* p, float v) { *p = f2bf(v); }

// async global->LDS, 16 B per lane; LDS dest = wave-uniform base + lane*16.
// Per-lane SOURCE addresses are arbitrary (gather) — verified rounds 2-5.
__device__ __forceinline__ void g2lds16(const void* g, void* l) {
    __builtin_amdgcn_global_load_lds(
        (const __attribute__((address_space(1))) void*)g,
        (__attribute__((address_space(3))) void*)l, 16, 0, 0);
}

// counted vmem wait: leave N loads in flight (never drain to 0 in main loop)
template <int N>
__device__ __forceinline__ void s_wait_vmcnt() {
    asm volatile("s_waitcnt vmcnt(%0)" :: "n"(N) : "memory");
}
__device__ __forceinline__ void s_wait_lgkm0() {
    asm volatile("s_waitcnt lgkmcnt(0)" ::: "memory");
}
// raw barrier as asm with memory clobber: no compiler-inserted vmcnt(0) drain,
// and no memory op (ds_read / global_load_lds) may be reordered across it.
__device__ __forceinline__ void s_bar() {
    asm volatile("s_barrier" ::: "memory");
}

// ---------------------------------------------------------------------------
// fp32 -> bf16 elementwise convert, 3 tensors in one launch (z selects).
// ---------------------------------------------------------------------------
__global__ __launch_bounds__(256) void cvt3_bf16_kernel(
    const float* __restrict__ s0, const float* __restrict__ s1,
    const float* __restrict__ s2,
    unsigned short* __restrict__ d0, unsigned short* __restrict__ d1,
    unsigned short* __restrict__ d2, int n)
{
    const float* src; unsigned short* dst;
    switch (blockIdx.z) {
        case 0:  src = s0; dst = d0; break;
        case 1:  src = s1; dst = d1; break;
        default: src = s2; dst = d2; break;
    }
    int i = (blockIdx.x * 256 + threadIdx.x) * 8;
    if (i >= n) return;
    float4 a = *(const float4*)(src + i);
    float4 b = *(const float4*)(src + i + 4);
    union { unsigned short s[8]; uint4 u; } o;
    o.s[0] = f2bf(a.x); o.s[1] = f2bf(a.y); o.s[2] = f2bf(a.z); o.s[3] = f2bf(a.w);
    o.s[4] = f2bf(b.x); o.s[5] = f2bf(b.y); o.s[6] = f2bf(b.z); o.s[7] = f2bf(b.w);
    *(uint4*)(dst + i) = o.u;
}

// ---------------------------------------------------------------------------
// Transpose + convert the 4 weight matrices: Wt[n][k] = (bf16)W[k][n], 1024^2.
// ---------------------------------------------------------------------------
__global__ __launch_bounds__(256) void wtrans_kernel(
    const float* __restrict__ w0, const float* __restrict__ w1,
    const float* __restrict__ w2, const float* __restrict__ w3,
    unsigned short* __restrict__ t0, unsigned short* __restrict__ t1,
    unsigned short* __restrict__ t2, unsigned short* __restrict__ t3)
{
    __shared__ float tile[32][33];
    const float* W; unsigned short* T;
    switch (blockIdx.z) {
        case 0:  W = w0; T = t0; break;
        case 1:  W = w1; T = t1; break;
        case 2:  W = w2; T = t2; break;
        default: W = w3; T = t3; break;
    }
    const int n0 = blockIdx.x * 32, k0 = blockIdx.y * 32;
    const int t  = threadIdx.x;
    const int r  = t >> 3;          // 0..31
    const int c4 = (t & 7) * 4;     // 0..28

    float4 v = *(const float4*)&W[(size_t)(k0 + r) * DMODEL + n0 + c4];
    tile[r][c4 + 0] = v.x; tile[r][c4 + 1] = v.y;
    tile[r][c4 + 2] = v.z; tile[r][c4 + 3] = v.w;
    __syncthreads();

    union { unsigned short s[4]; uint2 u; } o;
#pragma unroll
    for (int u = 0; u < 4; ++u) o.s[u] = f2bf(tile[c4 + u][r]);
    *(uint2*)&T[(size_t)(n0 + r) * DMODEL + k0 + c4] = o.u;
}

// ---------------------------------------------------------------------------
// MFMA GEMM, round-9 (= round-8 resubmit, hardened addressing):
// 256-row x (NC*16)-col tile, 8 waves (512 threads), double-buffered
// counted-vmcnt pipeline (race-verified skeleton from round 7:
// vmcnt(PW) -> bar -> ds_read+MFMA -> lgkm0 -> bar -> issue tile kt+2).
// Rationale: at K=1024 the 128^2 tile was staging-bound with ~1 block/CU
// (MfmaUtil 13%); 256-wide tiles double arithmetic intensity and give each
// K-step 64 MFMA/wave of latency-hiding work (m248: 256^2 @ K=1024 =
// 655-848 TF vs our 358).
//  - NC = number of 16-wide column groups (QKV: 16 -> 256 cols; outproj: 8)
//  - wave grid 2(M) x 4(N): per wave 128 rows x NC*4 cols, acc 8 x NC/4
//  - XCD-aware bijective remap over the full (x,z) grid (grid%8==0).
// ---------------------------------------------------------------------------
struct GemmP {
    const unsigned short* A;
    const unsigned short* Bt;
    const float* bias;
    void* C;
    int N, K, ctShift, biasByRow;
    float scale;
};
struct Gemm3 { GemmP p[3]; };

template <typename OutT, int NC>
__global__ __launch_bounds__(512, 2) void gemm_lds_kernel(Gemm3 g)
{
    constexpr int NCW   = NC / 4;            // per-wave column fragments
    constexpr int NBLK  = 32 + 2 * NC;       // 512-short staging blocks / buffer
    constexpr int PW    = NBLK / 8;          // staging loads per wave per K-step
    constexpr int BUFSZ = NBLK * 512;        // shorts per buffer

    __shared__ unsigned short sS[2 * BUFSZ]; // [buf0 | buf1]; A: blocks [0,32)

    // XCD-aware remap across the whole linear grid (launcher guarantees %8==0)
    const unsigned nx  = gridDim.x;
    const unsigned lin = blockIdx.x + nx * blockIdx.z;
    const unsigned ch  = (nx * gridDim.z) >> 3;
    const unsigned l2  = (lin & 7u) * ch + (lin >> 3);
    const unsigned zz  = l2 / nx;
    const unsigned bid = l2 - zz * nx;

    const GemmP p = g.p[zz];
    const unsigned short* __restrict__ A  = p.A;
    const unsigned short* __restrict__ Bt = p.Bt;
    OutT* __restrict__ C = (OutT*)p.C;
    const int K = p.K, N = p.N;

    const int bx = (int)(bid & ((1u << p.ctShift) - 1u));
    const int by = (int)(bid >> p.ctShift);
    const int row0 = by * 256;
    const int col0 = bx * (NC * 16);

    const int t    = threadIdx.x;
    const int w    = t >> 6;        // 0..7
    const int lane = t & 63;
    const int ln   = lane & 15;
    const int qg   = lane >> 4;
    const int wm   = w >> 2;        // 0..1  (128-row halves)
    const int wn   = w & 3;         // 0..3  (NC/4-wide col quarters)

    // wave-uniform staging assignments: blocks [0,32) = A, [32,32+2*NC) = B
    const unsigned short* sp[PW];
    int lo[PW];                     // LDS short-offset of block s in buffer 0
#pragma unroll
    for (int i = 0; i < PW; ++i) {
        const int s = w * PW + i;
        if (s < 32) {
            const int mtg = s >> 1, kc = s & 1;
            sp[i] = A + (size_t)(row0 + mtg * 16 + ln) * K + kc * 32 + qg * 8;
        } else {
            const int bi = s - 32;
            const int ntg = bi >> 1, kc = bi & 1;
            sp[i] = Bt + (size_t)(col0 + ntg * 16 + ln) * K + kc * 32 + qg * 8;
        }
        lo[i] = s * 512;
    }

    f32x4 acc[8][NCW];
#pragma unroll
    for (int mt = 0; mt < 8; ++mt)
#pragma unroll
        for (int nt = 0; nt < NCW; ++nt) acc[mt][nt] = (f32x4){0.f, 0.f, 0.f, 0.f};

    const int NT = K / 64;

    // ---- prologue: tiles 0 and 1 in flight ----
#pragma unroll
    for (int i = 0; i < PW; ++i) g2lds16(sp[i], &sS[lo[i]]);
#pragma unroll
    for (int i = 0; i < PW; ++i) g2lds16(sp[i] + 64, &sS[BUFSZ + lo[i]]);

    int curOff = 0;
    for (int kt = 0; kt < NT; ++kt) {
        // current tile's PW loads are the oldest; leave the next PW in flight
        if (kt < NT - 1) s_wait_vmcnt<PW>();
        else             s_wait_vmcnt<0>();
        s_bar();

        const unsigned short* bufA = &sS[curOff];
        const unsigned short* bufB = &sS[curOff + 32 * 512];
#pragma unroll
        for (int kc = 0; kc < 2; ++kc) {
            bf16x8 aF[8], bF[NCW];
#pragma unroll
            for (int mt = 0; mt < 8; ++mt)
                aF[mt] = *(const bf16x8*)&bufA[(((wm * 8 + mt) * 2) + kc) * 512 + lane * 8];
#pragma unroll
            for (int n2 = 0; n2 < NCW; ++n2)
                bF[n2] = *(const bf16x8*)&bufB[(((wn * NCW + n2) * 2) + kc) * 512 + lane * 8];
#pragma unroll
            for (int mt = 0; mt < 8; ++mt)
#pragma unroll
                for (int n2 = 0; n2 < NCW; ++n2)
                    acc[mt][n2] = __builtin_amdgcn_mfma_f32_16x16x32_bf16(
                        aF[mt], bF[n2], acc[mt][n2], 0, 0, 0);
        }

        // all of this wave's ds_reads must be COMPLETE (not just issued)
        // before anyone overwrites buf[cur] with tile kt+2
        s_wait_lgkm0();
        s_bar();

        if (kt + 2 < NT) {
            const int koff = (kt + 2) * 64;
#pragma unroll
            for (int i = 0; i < PW; ++i)
                g2lds16(sp[i] + koff, &sS[curOff + lo[i]]);
        }
        curOff ^= BUFSZ;
    }

    float bcol[NCW], brow[8][4];
    if (!p.biasByRow) {
#pragma unroll
        for (int n2 = 0; n2 < NCW; ++n2)
            bcol[n2] = p.bias[col0 + (wn * NCW + n2) * 16 + ln];
    } else {
#pragma unroll
        for (int mt = 0; mt < 8; ++mt)
#pragma unroll
            for (int r = 0; r < 4; ++r)
                brow[mt][r] = p.bias[row0 + wm * 128 + mt * 16 + qg * 4 + r];
    }

#pragma unroll
    for (int mt = 0; mt < 8; ++mt)
#pragma unroll
        for (int n2 = 0; n2 < NCW; ++n2)
#pragma unroll
            for (int r = 0; r < 4; ++r) {
                int row = row0 + wm * 128 + mt * 16 + qg * 4 + r;
                int col = col0 + (wn * NCW + n2) * 16 + ln;
                float bb = p.biasByRow ? brow[mt][r] : bcol[n2];
                store_out(&C[(size_t)row * N + col], (acc[mt][n2][r] + bb) * p.scale);
            }
}

// ---------------------------------------------------------------------------
// Flash attention, round-6 structure (unchanged this round):
//  - Q, K, V all staged fragment-ordered via global_load_lds (V comes from the
//    transposed projection VT[d][token] -> contiguous 16B per lane, no LDS
//    transpose, no scalar writes)
//  - double-buffered K/V: prefetch tile j+1 before computing tile j; ONE
//    barrier per tile, with the vmcnt drain overlapped by a full tile of work
//  - l (softmax denom) via MFMA row-sum against an all-ones B fragment
//  - scores arrive pre-scaled by 0.125*log2e (folded into Q projection) ->
//    softmax runs in exp2 domain with zero scale multiplies
// ---------------------------------------------------------------------------
#define BR 64
#define BC 64
#define PSTR 72

__global__ __launch_bounds__(256) void attn_mfma_kernel(
    const unsigned short* __restrict__ Qg, const unsigned short* __restrict__ Kg,
    const unsigned short* __restrict__ VT, unsigned short* __restrict__ O)
{
    __shared__ unsigned short sK[2][8 * 512];   // 16 KB
    __shared__ unsigned short sV[2][8 * 512];   // 16 KB
    __shared__ unsigned short sQ[8 * 512];      // 8 KB
    __shared__ unsigned short sP[BR * PSTR];    // 9 KB

    const int t    = threadIdx.x;
    const int w    = t >> 6;
    const int lane = t & 63;
    const int ln   = lane & 15;
    const int qg   = lane >> 4;

    const int id  = blockIdx.x;
    const int bh  = id & 31;
    const int qt  = (SEQ / BR - 1) - (id >> 5);   // heavy tiles first
    const int b   = bh >> 4;
    const int h   = bh & 15;
    const int qi0 = qt * BR;

    const size_t rowbase = (size_t)b * SEQ;
    const size_t colbase = (size_t)h * DK;

    // ---- stage Q + K/V tile 0 (buf 0) ----
#pragma unroll
    for (int i = 0; i < 2; ++i) {
        const int s = w * 2 + i;
        const int nt = s >> 1, kc = s & 1;
        g2lds16(Qg + (rowbase + qi0 + w * 16 + ln) * DMODEL + colbase + i * 32 + qg * 8,
                &sQ[s * 512]);
        g2lds16(Kg + (rowbase + nt * 16 + ln) * DMODEL + colbase + kc * 32 + qg * 8,
                &sK[0][s * 512]);
        g2lds16(VT + (size_t)(colbase + nt * 16 + ln) * MTOK + rowbase + kc * 32 + qg * 8,
                &sV[0][s * 512]);
    }
    __syncthreads();

    bf16x8 aq[2];
#pragma unroll
    for (int kc = 0; kc < 2; ++kc)
        aq[kc] = *(const bf16x8*)&sQ[(w * 2 + kc) * 512 + lane * 8];

    const short one_bf = (short)0x3F80;
    const bf16x8 bone = (bf16x8){one_bf, one_bf, one_bf, one_bf,
                                 one_bf, one_bf, one_bf, one_bf};

    f32x4 ofrag[4];
#pragma unroll
    for (int nt = 0; nt < 4; ++nt) ofrag[nt] = (f32x4){0.f, 0.f, 0.f, 0.f};
    f32x4 osum = (f32x4){0.f, 0.f, 0.f, 0.f};
    float m_r[4];
#pragma unroll
    for (int r = 0; r < 4; ++r) m_r[r] = -3.0e38f;

    const int ntiles = qt + 1;
    for (int jt = 0; jt < ntiles; ++jt) {
        const int cur = jt & 1;

        // ---- prefetch tile jt+1 into the alternate buffer (latency hidden
        //      behind this tile's compute; drained at the end barrier) ----
        if (jt + 1 < ntiles) {
            const int j1 = (jt + 1) * BC;
            const int nb = cur ^ 1;
#pragma unroll
            for (int i = 0; i < 2; ++i) {
                const int s = w * 2 + i;
                const int nt = s >> 1, kc = s & 1;
                g2lds16(Kg + (rowbase + j1 + nt * 16 + ln) * DMODEL + colbase + kc * 32 + qg * 8,
                        &sK[nb][s * 512]);
                g2lds16(VT + (size_t)(colbase + nt * 16 + ln) * MTOK + rowbase + j1 + kc * 32 + qg * 8,
                        &sV[nb][s * 512]);
            }
        }

        // ---- S = Q K^T (scores pre-scaled by 0.125*log2e) ----
        f32x4 sf[4];
#pragma unroll
        for (int nt = 0; nt < 4; ++nt) {
            f32x4 a2 = (f32x4){0.f, 0.f, 0.f, 0.f};
#pragma unroll
            for (int kc = 0; kc < 2; ++kc) {
                bf16x8 bk = *(const bf16x8*)&sK[cur][(nt * 2 + kc) * 512 + lane * 8];
                a2 = __builtin_amdgcn_mfma_f32_16x16x32_bf16(aq[kc], bk, a2, 0, 0, 0);
            }
            sf[nt] = a2;
        }

        // ---- causal mask (diagonal tile only) ----
        if (jt == ntiles - 1) {
#pragma unroll
            for (int nt = 0; nt < 4; ++nt)
#pragma unroll
                for (int r = 0; r < 4; ++r) {
                    int qrow = w * 16 + qg * 4 + r;
                    int col  = nt * 16 + ln;
                    if (col > qrow) sf[nt][r] = -1.0e30f;
                }
        }

        // ---- online softmax (exp2 domain); l via MFMA row-sum below ----
        float rmax[4];
#pragma unroll
        for (int r = 0; r < 4; ++r)
            rmax[r] = fmaxf(fmaxf(sf[0][r], sf[1][r]), fmaxf(sf[2][r], sf[3][r]));
#pragma unroll
        for (int off = 8; off >= 1; off >>= 1)
#pragma unroll
            for (int r = 0; r < 4; ++r)
                rmax[r] = fmaxf(rmax[r], __shfl_xor(rmax[r], off));

        float alpha[4];
#pragma unroll
        for (int r = 0; r < 4; ++r) {
            float mn = fmaxf(m_r[r], rmax[r]);
            alpha[r] = exp2f(m_r[r] - mn);
            m_r[r] = mn;
        }

#pragma unroll
        for (int nt = 0; nt < 4; ++nt)
#pragma unroll
            for (int r = 0; r < 4; ++r) {
                float pv = exp2f(sf[nt][r] - m_r[r]);
                int row = w * 16 + qg * 4 + r;
                int col = (nt * 16 + ln) ^ (((w * 4 + qg) & 7) * 8);
                sP[row * PSTR + col] = f2bf(pv);
            }

#pragma unroll
        for (int nt = 0; nt < 4; ++nt)
#pragma unroll
            for (int r = 0; r < 4; ++r) ofrag[nt][r] *= alpha[r];
#pragma unroll
        for (int r = 0; r < 4; ++r) osum[r] *= alpha[r];

        // ---- P back as A-fragments ----
        bf16x8 apf[2];
#pragma unroll
        for (int kc = 0; kc < 2; ++kc) {
            int row = w * 16 + ln;
            int col = (kc * 32 + qg * 8) ^ ((((row >> 2) & 7)) * 8);
            apf[kc] = *(const bf16x8*)&sP[row * PSTR + col];
        }

        // ---- O += P V ; l += P . ones (MFMA row-sum) ----
#pragma unroll
        for (int kc = 0; kc < 2; ++kc)
            osum = __builtin_amdgcn_mfma_f32_16x16x32_bf16(apf[kc], bone, osum, 0, 0, 0);
#pragma unroll
        for (int nt = 0; nt < 4; ++nt) {
#pragma unroll
            for (int kc = 0; kc < 2; ++kc) {
                bf16x8 bv = *(const bf16x8*)&sV[cur][(nt * 2 + kc) * 512 + lane * 8];
                ofrag[nt] = __builtin_amdgcn_mfma_f32_16x16x32_bf16(apf[kc], bv, ofrag[nt], 0, 0, 0);
            }
        }

        __syncthreads();    // publish prefetched tile; protect cur for overwrite
    }

    // ---- epilogue: normalize, write bf16 ctx in [B,S,D] layout ----
    float inv[4];
#pragma unroll
    for (int r = 0; r < 4; ++r) inv[r] = 1.0f / osum[r];
#pragma unroll
    for (int nt = 0; nt < 4; ++nt)
#pragma unroll
        for (int r = 0; r < 4; ++r) {
            int gq = qi0 + w * 16 + qg * 4 + r;
            O[(rowbase + gq) * DMODEL + colbase + nt * 16 + ln] =
                f2bf(ofrag[nt][r] * inv[r]);
        }
}

// ---------------------------------------------------------------------------
extern "C" void kernel_launch(void* const* d_in, const int* in_sizes, int n_in,
                              void* d_out, int out_size, void* d_ws, size_t ws_size,
                              hipStream_t stream)
{
    const float* q  = (const float*)d_in[0];
    const float* k  = (const float*)d_in[1];
    const float* v  = (const float*)d_in[2];
    // d_in[3] = mask (int32 tril) — causality applied analytically (j<=i).
    const float* wq = (const float*)d_in[4];
    const float* bq = (const float*)d_in[5];
    const float* wk = (const float*)d_in[6];
    const float* bk = (const float*)d_in[7];
    const float* wv = (const float*)d_in[8];
    const float* bv = (const float*)d_in[9];
    const float* wo = (const float*)d_in[10];
    const float* bo = (const float*)d_in[11];
    float* out = (float*)d_out;

    const size_t mat  = (size_t)MTOK * DMODEL;     // 4M elements
    const size_t wmat = (size_t)DMODEL * DMODEL;   // 1M elements
    unsigned short* Abq = (unsigned short*)d_ws;   // bf16 activations
    unsigned short* Abk = Abq + mat;
    unsigned short* Abv = Abk + mat;
    unsigned short* WtQ = Abv + mat;               // bf16 transposed weights
    unsigned short* WtK = WtQ + wmat;
    unsigned short* WtV = WtK + wmat;
    unsigned short* WtO = WtV + wmat;
    unsigned short* Qb  = WtO + wmat;              // bf16 Q proj (pre-scaled)
    unsigned short* Kb  = Qb + mat;                // bf16 K proj
    unsigned short* VT  = Kb + mat;                // bf16 V proj, TRANSPOSED [D][MTOK]
    unsigned short* CTX = VT + mat;                // bf16 attention output

    cvt3_bf16_kernel<<<dim3((unsigned)(mat / 2048), 1, 3), 256, 0, stream>>>(
        q, k, v, Abq, Abk, Abv, (int)mat);
    wtrans_kernel<<<dim3(32, 32, 4), 256, 0, stream>>>(wq, wk, wv, wo, WtQ, WtK, WtV, WtO);

    // fused projections: z0=Q (pre-scaled by 0.125*log2e), z1=K, z2=V transposed.
    // 256x256 tiles: z0/z1: 16x4 = 64 blocks (ctShift=2); z2 (swapped, C=VT
    // [1024 x 4096]): 4x16 = 64 blocks (ctShift=4). Total 192 (%8==0).
    const float qscale = 0.125f * 1.44269504088896f;
    Gemm3 g;
    g.p[0] = (GemmP){Abq, WtQ, bq, (void*)Qb, DMODEL, DMODEL, 2, 0, qscale};
    g.p[1] = (GemmP){Abk, WtK, bk, (void*)Kb, DMODEL, DMODEL, 2, 0, 1.0f};
    g.p[2] = (GemmP){WtV, Abv, bv, (void*)VT, MTOK,   DMODEL, 4, 1, 1.0f};  // swapped operands
    gemm_lds_kernel<unsigned short, 16><<<dim3(64, 1, 3), 512, 0, stream>>>(g);

    attn_mfma_kernel<<<BATCH * NHEAD * (SEQ / BR), 256, 0, stream>>>(Qb, Kb, VT, CTX);

    // output projection: 256x128 tiles -> 16x8 = 128 blocks (%8==0)
    Gemm3 go;
    go.p[0] = (GemmP){CTX, WtO, bo, (void*)out, DMODEL, DMODEL, 3, 0, 1.0f};
    go.p[1] = go.p[0];
    go.p[2] = go.p[0];
    gemm_lds_kernel<float, 8><<<dim3(128, 1, 1), 512, 0, stream>>>(go);
}

// Round 4
// 257.074 us; speedup vs baseline: 1.0517x; 1.0517x over previous
//
#include <hip/hip_runtime.h>
#include <hip/hip_bf16.h>

// Problem constants (from reference)
#define BATCH 2
#define SEQ   2048
#define DMODEL 1024
#define NHEAD 16
#define DK    64
#define MTOK  (BATCH * SEQ)      // 4096 token rows

typedef __attribute__((ext_vector_type(8))) short bf16x8;   // 8 bf16 in 4 VGPRs
typedef __attribute__((ext_vector_type(4))) float f32x4;    // MFMA 16x16 accumulator

// float -> bf16 bits, round-to-nearest-even
__device__ __forceinline__ unsigned short f2bf(float x) {
    unsigned u = __float_as_uint(x);
    u = (u + 0x7FFFu + ((u >> 16) & 1u)) >> 16;
    return (unsigned short)u;
}

__device__ __forceinline__ void store_out(float* p, float v)          { *p = v; }
__device__ __forceinline__ void store_out(unsigned short* p, float v) { *p = f2bf(v); }

// packed f32x2 -> bf16x2 (RNE), lo = x, hi = y
__device__ __forceinline__ unsigned cvt_pk_bf16(float x, float y) {
    unsigned d;
    asm("v_cvt_pk_bf16_f32 %0, %1, %2" : "=v"(d) : "v"(x), "v"(y));
    return d;
}

// async global->LDS, 16 B per lane; LDS dest = wave-uniform base + lane*16.
__device__ __forceinline__ void g2lds16(const void* g, void* l) {
    __builtin_amdgcn_global_load_lds(
        (const __attribute__((address_space(1))) void*)g,
        (__attribute__((address_space(3))) void*)l, 16, 0, 0);
}

// counted vmem wait: leave N loads in flight (never drain to 0 in main loop)
template <int N>
__device__ __forceinline__ void s_wait_vmcnt() {
    asm volatile("s_waitcnt vmcnt(%0)" :: "n"(N) : "memory");
}
__device__ __forceinline__ void s_wait_lgkm0() {
    asm volatile("s_waitcnt lgkmcnt(0)" ::: "memory");
}
__device__ __forceinline__ void s_bar() {
    asm volatile("s_barrier" ::: "memory");
}

// ---------------------------------------------------------------------------
// fp32 -> bf16 elementwise convert, 3 tensors in one launch (z selects).
// ---------------------------------------------------------------------------
__global__ __launch_bounds__(256) void cvt3_bf16_kernel(
    const float* __restrict__ s0, const float* __restrict__ s1,
    const float* __restrict__ s2,
    unsigned short* __restrict__ d0, unsigned short* __restrict__ d1,
    unsigned short* __restrict__ d2, int n)
{
    const float* src; unsigned short* dst;
    switch (blockIdx.z) {
        case 0:  src = s0; dst = d0; break;
        case 1:  src = s1; dst = d1; break;
        default: src = s2; dst = d2; break;
    }
    int i = (blockIdx.x * 256 + threadIdx.x) * 8;
    if (i >= n) return;
    float4 a = *(const float4*)(src + i);
    float4 b = *(const float4*)(src + i + 4);
    union { unsigned short s[8]; uint4 u; } o;
    o.s[0] = f2bf(a.x); o.s[1] = f2bf(a.y); o.s[2] = f2bf(a.z); o.s[3] = f2bf(a.w);
    o.s[4] = f2bf(b.x); o.s[5] = f2bf(b.y); o.s[6] = f2bf(b.z); o.s[7] = f2bf(b.w);
    *(uint4*)(dst + i) = o.u;
}

// ---------------------------------------------------------------------------
// Transpose + convert the 4 weight matrices: Wt[n][k] = (bf16)W[k][n], 1024^2.
// ---------------------------------------------------------------------------
__global__ __launch_bounds__(256) void wtrans_kernel(
    const float* __restrict__ w0, const float* __restrict__ w1,
    const float* __restrict__ w2, const float* __restrict__ w3,
    unsigned short* __restrict__ t0, unsigned short* __restrict__ t1,
    unsigned short* __restrict__ t2, unsigned short* __restrict__ t3)
{
    __shared__ float tile[32][33];
    const float* W; unsigned short* T;
    switch (blockIdx.z) {
        case 0:  W = w0; T = t0; break;
        case 1:  W = w1; T = t1; break;
        case 2:  W = w2; T = t2; break;
        default: W = w3; T = t3; break;
    }
    const int n0 = blockIdx.x * 32, k0 = blockIdx.y * 32;
    const int t  = threadIdx.x;
    const int r  = t >> 3;          // 0..31
    const int c4 = (t & 7) * 4;     // 0..28

    float4 v = *(const float4*)&W[(size_t)(k0 + r) * DMODEL + n0 + c4];
    tile[r][c4 + 0] = v.x; tile[r][c4 + 1] = v.y;
    tile[r][c4 + 2] = v.z; tile[r][c4 + 3] = v.w;
    __syncthreads();

    union { unsigned short s[4]; uint2 u; } o;
#pragma unroll
    for (int u = 0; u < 4; ++u) o.s[u] = f2bf(tile[c4 + u][r]);
    *(uint2*)&T[(size_t)(n0 + r) * DMODEL + k0 + c4] = o.u;
}

// ---------------------------------------------------------------------------
// MFMA GEMM: (MR*16)-row x (NC*16)-col tile, 8 waves (512 threads),
// double-buffered counted-vmcnt pipeline (race-verified skeleton:
// vmcnt(PW) -> bar -> ds_read+MFMA -> lgkm0 -> bar -> issue tile kt+2).
//  - QKV: MR=16,NC=16 (256x256); outproj: MR=8,NC=8 (128x128, 256 blocks
//    so the whole chip is busy at 2 blocks/CU instead of half idle at 1)
//  - wave grid 2(M) x 4(N); XCD-aware bijective remap (grid%8==0).
// ---------------------------------------------------------------------------
struct GemmP {
    const unsigned short* A;
    const unsigned short* Bt;
    const float* bias;
    void* C;
    int N, K, ctShift, biasByRow;
    float scale;
};
struct Gemm3 { GemmP p[3]; };

template <typename OutT, int MR, int NC>
__global__ __launch_bounds__(512, 2) void gemm_lds_kernel(Gemm3 g)
{
    constexpr int AM    = MR / 2;            // per-wave row fragments
    constexpr int NCW   = NC / 4;            // per-wave column fragments
    constexpr int NBLK  = 2 * MR + 2 * NC;   // 512-short staging blocks / buffer
    constexpr int PW    = NBLK / 8;          // staging loads per wave per K-step
    constexpr int BUFSZ = NBLK * 512;        // shorts per buffer

    __shared__ unsigned short sS[2 * BUFSZ]; // [buf0 | buf1]; A blocks first

    // XCD-aware remap across the whole linear grid (launcher guarantees %8==0)
    const unsigned nx  = gridDim.x;
    const unsigned lin = blockIdx.x + nx * blockIdx.z;
    const unsigned ch  = (nx * gridDim.z) >> 3;
    const unsigned l2  = (lin & 7u) * ch + (lin >> 3);
    const unsigned zz  = l2 / nx;
    const unsigned bid = l2 - zz * nx;

    const GemmP p = g.p[zz];
    const unsigned short* __restrict__ A  = p.A;
    const unsigned short* __restrict__ Bt = p.Bt;
    OutT* __restrict__ C = (OutT*)p.C;
    const int K = p.K, N = p.N;

    const int bx = (int)(bid & ((1u << p.ctShift) - 1u));
    const int by = (int)(bid >> p.ctShift);
    const int row0 = by * (MR * 16);
    const int col0 = bx * (NC * 16);

    const int t    = threadIdx.x;
    const int w    = t >> 6;        // 0..7
    const int lane = t & 63;
    const int ln   = lane & 15;
    const int qg   = lane >> 4;
    const int wm   = w >> 2;        // 0..1  (row halves)
    const int wn   = w & 3;         // 0..3  (col quarters)

    // wave-uniform staging assignments: blocks [0,2*MR) = A, rest = B
    const unsigned short* sp[PW];
    int lo[PW];
#pragma unroll
    for (int i = 0; i < PW; ++i) {
        const int s = w * PW + i;
        if (s < 2 * MR) {
            const int mtg = s >> 1, kc = s & 1;
            sp[i] = A + (size_t)(row0 + mtg * 16 + ln) * K + kc * 32 + qg * 8;
        } else {
            const int bi = s - 2 * MR;
            const int ntg = bi >> 1, kc = bi & 1;
            sp[i] = Bt + (size_t)(col0 + ntg * 16 + ln) * K + kc * 32 + qg * 8;
        }
        lo[i] = s * 512;
    }

    f32x4 acc[AM][NCW];
#pragma unroll
    for (int mt = 0; mt < AM; ++mt)
#pragma unroll
        for (int nt = 0; nt < NCW; ++nt) acc[mt][nt] = (f32x4){0.f, 0.f, 0.f, 0.f};

    const int NT = K / 64;

    // ---- prologue: tiles 0 and 1 in flight ----
#pragma unroll
    for (int i = 0; i < PW; ++i) g2lds16(sp[i], &sS[lo[i]]);
#pragma unroll
    for (int i = 0; i < PW; ++i) g2lds16(sp[i] + 64, &sS[BUFSZ + lo[i]]);

    int curOff = 0;
    for (int kt = 0; kt < NT; ++kt) {
        if (kt < NT - 1) s_wait_vmcnt<PW>();
        else             s_wait_vmcnt<0>();
        s_bar();

        const unsigned short* bufA = &sS[curOff];
        const unsigned short* bufB = &sS[curOff + 2 * MR * 512];
#pragma unroll
        for (int kc = 0; kc < 2; ++kc) {
            bf16x8 aF[AM], bF[NCW];
#pragma unroll
            for (int mt = 0; mt < AM; ++mt)
                aF[mt] = *(const bf16x8*)&bufA[(((wm * AM + mt) * 2) + kc) * 512 + lane * 8];
#pragma unroll
            for (int n2 = 0; n2 < NCW; ++n2)
                bF[n2] = *(const bf16x8*)&bufB[(((wn * NCW + n2) * 2) + kc) * 512 + lane * 8];
#pragma unroll
            for (int mt = 0; mt < AM; ++mt)
#pragma unroll
                for (int n2 = 0; n2 < NCW; ++n2)
                    acc[mt][n2] = __builtin_amdgcn_mfma_f32_16x16x32_bf16(
                        aF[mt], bF[n2], acc[mt][n2], 0, 0, 0);
        }

        s_wait_lgkm0();
        s_bar();

        if (kt + 2 < NT) {
            const int koff = (kt + 2) * 64;
#pragma unroll
            for (int i = 0; i < PW; ++i)
                g2lds16(sp[i] + koff, &sS[curOff + lo[i]]);
        }
        curOff ^= BUFSZ;
    }

    float bcol[NCW], brow[AM][4];
    if (!p.biasByRow) {
#pragma unroll
        for (int n2 = 0; n2 < NCW; ++n2)
            bcol[n2] = p.bias[col0 + (wn * NCW + n2) * 16 + ln];
    } else {
#pragma unroll
        for (int mt = 0; mt < AM; ++mt)
#pragma unroll
            for (int r = 0; r < 4; ++r)
                brow[mt][r] = p.bias[row0 + wm * (AM * 16) + mt * 16 + qg * 4 + r];
    }

#pragma unroll
    for (int mt = 0; mt < AM; ++mt)
#pragma unroll
        for (int n2 = 0; n2 < NCW; ++n2)
#pragma unroll
            for (int r = 0; r < 4; ++r) {
                int row = row0 + wm * (AM * 16) + mt * 16 + qg * 4 + r;
                int col = col0 + (wn * NCW + n2) * 16 + ln;
                float bb = p.biasByRow ? brow[mt][r] : bcol[n2];
                store_out(&C[(size_t)row * N + col], (acc[mt][n2][r] + bb) * p.scale);
            }
}

// ---------------------------------------------------------------------------
// Flash attention, round-10: SWAPPED QK^T — softmax axis is lane-local.
// A- and B-fragments of mfma_16x16x32 share the same register layout
// (lane&15 = row/col, lane>>4 = k-octet), so mfma(K,Q) gives S^T with
// q = lane&15: each lane owns one q-row (16-wide k-slice). Softmax state
// (m, alpha, l) becomes per-lane SCALAR; max-reduce is 15 local fmax +
// 2 shfl_xor; P never touches LDS — 8 v_cvt_pk_bf16_f32 + 16 ds_bpermute
// + 8 cndmask rebuild the PV A-fragments in-register. Was: 48-op f2bf +
// 16 scalar LDS writes + swizzled reads + ones-MFMA row-sum (VALUBusy 64%,
// MfmaUtil 12.5%). sP removed: LDS 50->40 KB (4 blocks/CU).
// ---------------------------------------------------------------------------
#define BR 64
#define BC 64

__global__ __launch_bounds__(256) void attn_mfma_kernel(
    const unsigned short* __restrict__ Qg, const unsigned short* __restrict__ Kg,
    const unsigned short* __restrict__ VT, unsigned short* __restrict__ O)
{
    __shared__ unsigned short sK[2][8 * 512];   // 16 KB
    __shared__ unsigned short sV[2][8 * 512];   // 16 KB
    __shared__ unsigned short sQ[8 * 512];      // 8 KB

    const int t    = threadIdx.x;
    const int w    = t >> 6;
    const int lane = t & 63;
    const int ln   = lane & 15;
    const int qg   = lane >> 4;

    const int id  = blockIdx.x;
    const int bh  = id & 31;
    const int qt  = (SEQ / BR - 1) - (id >> 5);   // heavy tiles first
    const int b   = bh >> 4;
    const int h   = bh & 15;
    const int qi0 = qt * BR;

    const size_t rowbase = (size_t)b * SEQ;
    const size_t colbase = (size_t)h * DK;

    // ---- stage Q + K/V tile 0 (buf 0) ----
#pragma unroll
    for (int i = 0; i < 2; ++i) {
        const int s = w * 2 + i;
        const int nt = s >> 1, kc = s & 1;
        g2lds16(Qg + (rowbase + qi0 + w * 16 + ln) * DMODEL + colbase + i * 32 + qg * 8,
                &sQ[s * 512]);
        g2lds16(Kg + (rowbase + nt * 16 + ln) * DMODEL + colbase + kc * 32 + qg * 8,
                &sK[0][s * 512]);
        g2lds16(VT + (size_t)(colbase + nt * 16 + ln) * MTOK + rowbase + kc * 32 + qg * 8,
                &sV[0][s * 512]);
    }
    __syncthreads();

    // Q as B-fragment: lane holds Q[q=w*16+ln][d=kc*32+qg*8+j]
    bf16x8 aq[2];
#pragma unroll
    for (int kc = 0; kc < 2; ++kc)
        aq[kc] = *(const bf16x8*)&sQ[(w * 2 + kc) * 512 + lane * 8];

    f32x4 ofrag[4];
#pragma unroll
    for (int nt = 0; nt < 4; ++nt) ofrag[nt] = (f32x4){0.f, 0.f, 0.f, 0.f};
    float osum_p = 0.f;          // per-lane partial denom (own k-slice of q=ln)
    float m_run  = -3.0e38f;     // per-lane running max for q=ln

    // bpermute source lanes for the P-fragment exchange
    const int laneA = ((2 * qg) & 3) * 16 + ln;
    const int laneB = ((2 * qg + 1) & 3) * 16 + ln;
    const bool hiSel = (qg >> 1) & 1;

    const int ntiles = qt + 1;
    for (int jt = 0; jt < ntiles; ++jt) {
        const int cur = jt & 1;

        // ---- prefetch tile jt+1 into the alternate buffer ----
        if (jt + 1 < ntiles) {
            const int j1 = (jt + 1) * BC;
            const int nb = cur ^ 1;
#pragma unroll
            for (int i = 0; i < 2; ++i) {
                const int s = w * 2 + i;
                const int nt = s >> 1, kc = s & 1;
                g2lds16(Kg + (rowbase + j1 + nt * 16 + ln) * DMODEL + colbase + kc * 32 + qg * 8,
                        &sK[nb][s * 512]);
                g2lds16(VT + (size_t)(colbase + nt * 16 + ln) * MTOK + rowbase + j1 + kc * 32 + qg * 8,
                        &sV[nb][s * 512]);
            }
        }

        // ---- S^T = K Q^T (scores pre-scaled by 0.125*log2e) ----
        // sf[nt][r] = S[q=ln][k=nt*16+qg*4+r]
        f32x4 sf[4];
#pragma unroll
        for (int nt = 0; nt < 4; ++nt) {
            f32x4 a2 = (f32x4){0.f, 0.f, 0.f, 0.f};
#pragma unroll
            for (int kc = 0; kc < 2; ++kc) {
                bf16x8 bk = *(const bf16x8*)&sK[cur][(nt * 2 + kc) * 512 + lane * 8];
                a2 = __builtin_amdgcn_mfma_f32_16x16x32_bf16(bk, aq[kc], a2, 0, 0, 0);
            }
            sf[nt] = a2;
        }

        // ---- causal mask (diagonal tile only): k_local > q_local ----
        if (jt == ntiles - 1) {
            const int qloc = w * 16 + ln;
#pragma unroll
            for (int nt = 0; nt < 4; ++nt)
#pragma unroll
                for (int r = 0; r < 4; ++r)
                    if (nt * 16 + qg * 4 + r > qloc) sf[nt][r] = -1.0e30f;
        }

        // ---- online softmax, q-local: scalar m/alpha per lane ----
        float pmax = sf[0][0];
#pragma unroll
        for (int nt = 0; nt < 4; ++nt)
#pragma unroll
            for (int r = 0; r < 4; ++r) pmax = fmaxf(pmax, sf[nt][r]);
        pmax = fmaxf(pmax, __shfl_xor(pmax, 16));
        pmax = fmaxf(pmax, __shfl_xor(pmax, 32));

        const float mn = fmaxf(m_run, pmax);
        const float al = exp2f(m_run - mn);
        m_run = mn;

        float pv[4][4];
        float lsum = 0.f;
#pragma unroll
        for (int nt = 0; nt < 4; ++nt)
#pragma unroll
            for (int r = 0; r < 4; ++r) {
                float e = exp2f(sf[nt][r] - mn);
                pv[nt][r] = e;
                lsum += e;
            }
        osum_p = osum_p * al + lsum;

        // rescale O accumulator rows (row q = qg*4+r needs alpha from lane q)
        float alr[4];
#pragma unroll
        for (int r = 0; r < 4; ++r) alr[r] = __shfl(al, qg * 4 + r);
#pragma unroll
        for (int nt = 0; nt < 4; ++nt)
#pragma unroll
            for (int r = 0; r < 4; ++r) ofrag[nt][r] *= alr[r];

        // ---- pack P to bf16 pairs, exchange into PV A-fragments ----
        // pk[nt][rr] = bf16x2 of P[q=ln][k=16nt+4qg+2rr .. +1]
        unsigned pk0[2], pk1[2], pk2[2], pk3[2];
#pragma unroll
        for (int rr = 0; rr < 2; ++rr) {
            pk0[rr] = cvt_pk_bf16(pv[0][2 * rr], pv[0][2 * rr + 1]);
            pk1[rr] = cvt_pk_bf16(pv[1][2 * rr], pv[1][2 * rr + 1]);
            pk2[rr] = cvt_pk_bf16(pv[2][2 * rr], pv[2][2 * rr + 1]);
            pk3[rr] = cvt_pk_bf16(pv[3][2 * rr], pv[3][2 * rr + 1]);
        }
        // target: ap[kc] short j holds P[q=ln][k=kc*32+qg*8+j]
        union { bf16x8 v; unsigned u[4]; } ap[2];
        {
            unsigned s0, s1;
            // kc = 0: regs pk0/pk1
            s0 = (unsigned)__shfl((int)pk0[0], laneA); s1 = (unsigned)__shfl((int)pk1[0], laneA);
            ap[0].u[0] = hiSel ? s1 : s0;
            s0 = (unsigned)__shfl((int)pk0[1], laneA); s1 = (unsigned)__shfl((int)pk1[1], laneA);
            ap[0].u[1] = hiSel ? s1 : s0;
            s0 = (unsigned)__shfl((int)pk0[0], laneB); s1 = (unsigned)__shfl((int)pk1[0], laneB);
            ap[0].u[2] = hiSel ? s1 : s0;
            s0 = (unsigned)__shfl((int)pk0[1], laneB); s1 = (unsigned)__shfl((int)pk1[1], laneB);
            ap[0].u[3] = hiSel ? s1 : s0;
            // kc = 1: regs pk2/pk3
            s0 = (unsigned)__shfl((int)pk2[0], laneA); s1 = (unsigned)__shfl((int)pk3[0], laneA);
            ap[1].u[0] = hiSel ? s1 : s0;
            s0 = (unsigned)__shfl((int)pk2[1], laneA); s1 = (unsigned)__shfl((int)pk3[1], laneA);
            ap[1].u[1] = hiSel ? s1 : s0;
            s0 = (unsigned)__shfl((int)pk2[0], laneB); s1 = (unsigned)__shfl((int)pk3[0], laneB);
            ap[1].u[2] = hiSel ? s1 : s0;
            s0 = (unsigned)__shfl((int)pk2[1], laneB); s1 = (unsigned)__shfl((int)pk3[1], laneB);
            ap[1].u[3] = hiSel ? s1 : s0;
        }

        // ---- O += P V ----
#pragma unroll
        for (int nt = 0; nt < 4; ++nt) {
#pragma unroll
            for (int kc = 0; kc < 2; ++kc) {
                bf16x8 bv = *(const bf16x8*)&sV[cur][(nt * 2 + kc) * 512 + lane * 8];
                ofrag[nt] = __builtin_amdgcn_mfma_f32_16x16x32_bf16(ap[kc].v, bv, ofrag[nt], 0, 0, 0);
            }
        }

        __syncthreads();    // publish prefetched tile; protect cur for overwrite
    }

    // ---- epilogue: finish denom across k-slices, normalize, write bf16 ----
    float osum = osum_p + __shfl_xor(osum_p, 16);
    osum += __shfl_xor(osum, 32);
    const float invq = 1.0f / osum;     // lane's q = ln
    float inv[4];
#pragma unroll
    for (int r = 0; r < 4; ++r) inv[r] = __shfl(invq, qg * 4 + r);
#pragma unroll
    for (int nt = 0; nt < 4; ++nt)
#pragma unroll
        for (int r = 0; r < 4; ++r) {
            int gq = qi0 + w * 16 + qg * 4 + r;
            O[(rowbase + gq) * DMODEL + colbase + nt * 16 + ln] =
                f2bf(ofrag[nt][r] * inv[r]);
        }
}

// ---------------------------------------------------------------------------
extern "C" void kernel_launch(void* const* d_in, const int* in_sizes, int n_in,
                              void* d_out, int out_size, void* d_ws, size_t ws_size,
                              hipStream_t stream)
{
    const float* q  = (const float*)d_in[0];
    const float* k  = (const float*)d_in[1];
    const float* v  = (const float*)d_in[2];
    // d_in[3] = mask (int32 tril) — causality applied analytically (j<=i).
    const float* wq = (const float*)d_in[4];
    const float* bq = (const float*)d_in[5];
    const float* wk = (const float*)d_in[6];
    const float* bk = (const float*)d_in[7];
    const float* wv = (const float*)d_in[8];
    const float* bv = (const float*)d_in[9];
    const float* wo = (const float*)d_in[10];
    const float* bo = (const float*)d_in[11];
    float* out = (float*)d_out;

    const size_t mat  = (size_t)MTOK * DMODEL;     // 4M elements
    const size_t wmat = (size_t)DMODEL * DMODEL;   // 1M elements
    unsigned short* Abq = (unsigned short*)d_ws;   // bf16 activations
    unsigned short* Abk = Abq + mat;
    unsigned short* Abv = Abk + mat;
    unsigned short* WtQ = Abv + mat;               // bf16 transposed weights
    unsigned short* WtK = WtQ + wmat;
    unsigned short* WtV = WtK + wmat;
    unsigned short* WtO = WtV + wmat;
    unsigned short* Qb  = WtO + wmat;              // bf16 Q proj (pre-scaled)
    unsigned short* Kb  = Qb + mat;                // bf16 K proj
    unsigned short* VT  = Kb + mat;                // bf16 V proj, TRANSPOSED [D][MTOK]
    unsigned short* CTX = VT + mat;                // bf16 attention output

    cvt3_bf16_kernel<<<dim3((unsigned)(mat / 2048), 1, 3), 256, 0, stream>>>(
        q, k, v, Abq, Abk, Abv, (int)mat);
    wtrans_kernel<<<dim3(32, 32, 4), 256, 0, stream>>>(wq, wk, wv, wo, WtQ, WtK, WtV, WtO);

    // fused projections: z0=Q (pre-scaled by 0.125*log2e), z1=K, z2=V transposed.
    // 256x256 tiles: z0/z1: 16x4 = 64 blocks (ctShift=2); z2 (swapped, C=VT
    // [1024 x 4096]): 4x16 = 64 blocks (ctShift=4). Total 192 (%8==0).
    const float qscale = 0.125f * 1.44269504088896f;
    Gemm3 g;
    g.p[0] = (GemmP){Abq, WtQ, bq, (void*)Qb, DMODEL, DMODEL, 2, 0, qscale};
    g.p[1] = (GemmP){Abk, WtK, bk, (void*)Kb, DMODEL, DMODEL, 2, 0, 1.0f};
    g.p[2] = (GemmP){WtV, Abv, bv, (void*)VT, MTOK,   DMODEL, 4, 1, 1.0f};  // swapped operands
    gemm_lds_kernel<unsigned short, 16, 16><<<dim3(64, 1, 3), 512, 0, stream>>>(g);

    attn_mfma_kernel<<<BATCH * NHEAD * (SEQ / BR), 256, 0, stream>>>(Qb, Kb, VT, CTX);

    // output projection: 128x128 tiles -> 32x8 = 256 blocks (1/CU, 2 resident
    // possible at 64 KB LDS), full chip instead of 128 blocks on 256 CUs
    Gemm3 go;
    go.p[0] = (GemmP){CTX, WtO, bo, (void*)out, DMODEL, DMODEL, 3, 0, 1.0f};
    go.p[1] = go.p[0];
    go.p[2] = go.p[0];
    gemm_lds_kernel<float, 8, 8><<<dim3(256, 1, 1), 512, 0, stream>>>(go);
}

// Round 5
// 256.442 us; speedup vs baseline: 1.0543x; 1.0025x over previous
//
#include <hip/hip_runtime.h>
#include <hip/hip_bf16.h>

// Problem constants (from reference)
#define BATCH 2
#define SEQ   2048
#define DMODEL 1024
#define NHEAD 16
#define DK    64
#define MTOK  (BATCH * SEQ)      // 4096 token rows

typedef __attribute__((ext_vector_type(8))) short bf16x8;   // 8 bf16 in 4 VGPRs
typedef __attribute__((ext_vector_type(4))) float f32x4;    // MFMA 16x16 accumulator

// float -> bf16 bits, round-to-nearest-even
__device__ __forceinline__ unsigned short f2bf(float x) {
    unsigned u = __float_as_uint(x);
    u = (u + 0x7FFFu + ((u >> 16) & 1u)) >> 16;
    return (unsigned short)u;
}

__device__ __forceinline__ void store_out(float* p, float v)          { *p = v; }
__device__ __forceinline__ void store_out(unsigned short* p, float v) { *p = f2bf(v); }

// packed f32x2 -> bf16x2 (RNE), lo = x, hi = y
__device__ __forceinline__ unsigned cvt_pk_bf16(float x, float y) {
    unsigned d;
    asm("v_cvt_pk_bf16_f32 %0, %1, %2" : "=v"(d) : "v"(x), "v"(y));
    return d;
}

// async global->LDS, 16 B per lane; LDS dest = wave-uniform base + lane*16.
__device__ __forceinline__ void g2lds16(const void* g, void* l) {
    __builtin_amdgcn_global_load_lds(
        (const __attribute__((address_space(1))) void*)g,
        (__attribute__((address_space(3))) void*)l, 16, 0, 0);
}

// counted vmem wait: leave N loads in flight (never drain to 0 in main loop)
template <int N>
__device__ __forceinline__ void s_wait_vmcnt() {
    asm volatile("s_waitcnt vmcnt(%0)" :: "n"(N) : "memory");
}
__device__ __forceinline__ void s_wait_lgkm0() {
    asm volatile("s_waitcnt lgkmcnt(0)" ::: "memory");
}
__device__ __forceinline__ void s_bar() {
    asm volatile("s_barrier" ::: "memory");
}

// ---------------------------------------------------------------------------
// fp32 -> bf16 elementwise convert, 3 tensors in one launch (z selects).
// ---------------------------------------------------------------------------
__global__ __launch_bounds__(256) void cvt3_bf16_kernel(
    const float* __restrict__ s0, const float* __restrict__ s1,
    const float* __restrict__ s2,
    unsigned short* __restrict__ d0, unsigned short* __restrict__ d1,
    unsigned short* __restrict__ d2, int n)
{
    const float* src; unsigned short* dst;
    switch (blockIdx.z) {
        case 0:  src = s0; dst = d0; break;
        case 1:  src = s1; dst = d1; break;
        default: src = s2; dst = d2; break;
    }
    int i = (blockIdx.x * 256 + threadIdx.x) * 8;
    if (i >= n) return;
    float4 a = *(const float4*)(src + i);
    float4 b = *(const float4*)(src + i + 4);
    union { unsigned short s[8]; uint4 u; } o;
    o.s[0] = f2bf(a.x); o.s[1] = f2bf(a.y); o.s[2] = f2bf(a.z); o.s[3] = f2bf(a.w);
    o.s[4] = f2bf(b.x); o.s[5] = f2bf(b.y); o.s[6] = f2bf(b.z); o.s[7] = f2bf(b.w);
    *(uint4*)(dst + i) = o.u;
}

// ---------------------------------------------------------------------------
// Transpose + convert the 4 weight matrices: Wt[n][k] = (bf16)W[k][n], 1024^2.
// ---------------------------------------------------------------------------
__global__ __launch_bounds__(256) void wtrans_kernel(
    const float* __restrict__ w0, const float* __restrict__ w1,
    const float* __restrict__ w2, const float* __restrict__ w3,
    unsigned short* __restrict__ t0, unsigned short* __restrict__ t1,
    unsigned short* __restrict__ t2, unsigned short* __restrict__ t3)
{
    __shared__ float tile[32][33];
    const float* W; unsigned short* T;
    switch (blockIdx.z) {
        case 0:  W = w0; T = t0; break;
        case 1:  W = w1; T = t1; break;
        case 2:  W = w2; T = t2; break;
        default: W = w3; T = t3; break;
    }
    const int n0 = blockIdx.x * 32, k0 = blockIdx.y * 32;
    const int t  = threadIdx.x;
    const int r  = t >> 3;          // 0..31
    const int c4 = (t & 7) * 4;     // 0..28

    float4 v = *(const float4*)&W[(size_t)(k0 + r) * DMODEL + n0 + c4];
    tile[r][c4 + 0] = v.x; tile[r][c4 + 1] = v.y;
    tile[r][c4 + 2] = v.z; tile[r][c4 + 3] = v.w;
    __syncthreads();

    union { unsigned short s[4]; uint2 u; } o;
#pragma unroll
    for (int u = 0; u < 4; ++u) o.s[u] = f2bf(tile[c4 + u][r]);
    *(uint2*)&T[(size_t)(n0 + r) * DMODEL + k0 + c4] = o.u;
}

// ---------------------------------------------------------------------------
// MFMA GEMM, round-11: half-step pipeline (BK-half = 32), 3 half-steps of
// landing window. LDS = 2 buffers x 2 kc-regions; half-step h computes
// region h (buffer (h&2)/2, kc h&1) and stages h+4 into the SAME region
// (h+4 preserves bits 0 and 1) right after it is retired by lgkm0+barrier.
// vmcnt ladder 3HL/2HL/HL/0 (HL = loads per wave per half-step) keeps 3
// half-steps in flight, so each 32 KB stage gets ~3 compute phases to land
// (was: 64 KB tile with a 1-iteration window -> ~6k cyc/step dead time,
// MfmaUtil 15.6%). T5 setprio around the MFMA cluster (phase-split now).
// Verified invariants kept: wait-own-loads -> bar -> read+MFMA -> lgkm0 ->
// bar -> issue into freed region.
//  - QKV: MR=16,NC=16 (256x256); outproj: MR=8,NC=8 (128x128, 256 blocks)
//  - wave grid 2(M) x 4(N); XCD-aware bijective remap (grid%8==0).
// ---------------------------------------------------------------------------
struct GemmP {
    const unsigned short* A;
    const unsigned short* Bt;
    const float* bias;
    void* C;
    int N, K, ctShift, biasByRow;
    float scale;
};
struct Gemm3 { GemmP p[3]; };

template <typename OutT, int MR, int NC>
__global__ __launch_bounds__(512, 2) void gemm_lds_kernel(Gemm3 g)
{
    constexpr int AM    = MR / 2;            // per-wave row fragments
    constexpr int NCW   = NC / 4;            // per-wave column fragments
    constexpr int HL    = (MR + NC) / 8;     // stage loads / wave / half-step
    constexpr int BUFSZ = (2 * MR + 2 * NC) * 512;  // shorts per buffer

    __shared__ unsigned short sS[2 * BUFSZ];
    // region layout inside a buffer: [A kc0 | A kc1 | B kc0 | B kc1]
    //   A kc: blocks [kc*MR, kc*MR+MR)        (block j = rows j*16..+16, 32 k)
    //   B kc: blocks [2*MR + kc*NC, ... +NC)

    // XCD-aware remap across the whole linear grid (launcher guarantees %8==0)
    const unsigned nx  = gridDim.x;
    const unsigned lin = blockIdx.x + nx * blockIdx.z;
    const unsigned ch  = (nx * gridDim.z) >> 3;
    const unsigned l2  = (lin & 7u) * ch + (lin >> 3);
    const unsigned zz  = l2 / nx;
    const unsigned bid = l2 - zz * nx;

    const GemmP p = g.p[zz];
    const unsigned short* __restrict__ A  = p.A;
    const unsigned short* __restrict__ Bt = p.Bt;
    OutT* __restrict__ C = (OutT*)p.C;
    const int K = p.K, N = p.N;

    const int bx = (int)(bid & ((1u << p.ctShift) - 1u));
    const int by = (int)(bid >> p.ctShift);
    const int row0 = by * (MR * 16);
    const int col0 = bx * (NC * 16);

    const int t    = threadIdx.x;
    const int w    = t >> 6;        // 0..7
    const int lane = t & 63;
    const int ln   = lane & 15;
    const int qg   = lane >> 4;
    const int wm   = w >> 2;        // 0..1  (row halves)
    const int wn   = w & 3;         // 0..3  (col quarters)

    // wave-uniform staging assignment for one kc-half: blocks [0,MR)=A, rest=B
    const unsigned short* sp[HL];   // source base at k = qg*8 (kc-independent)
    int d0[HL];                     // LDS short-offset of dest block at kc=0
    int dk[HL];                     // extra offset when kc=1
#pragma unroll
    for (int i = 0; i < HL; ++i) {
        const int j = w * HL + i;
        if (j < MR) {
            sp[i] = A + (size_t)(row0 + j * 16 + ln) * K + qg * 8;
            d0[i] = j * 512;
            dk[i] = MR * 512;
        } else {
            sp[i] = Bt + (size_t)(col0 + (j - MR) * 16 + ln) * K + qg * 8;
            d0[i] = (2 * MR + (j - MR)) * 512;
            dk[i] = NC * 512;
        }
    }

    f32x4 acc[AM][NCW];
#pragma unroll
    for (int mt = 0; mt < AM; ++mt)
#pragma unroll
        for (int nt = 0; nt < NCW; ++nt) acc[mt][nt] = (f32x4){0.f, 0.f, 0.f, 0.f};

    const int NH = K / 32;          // half-steps (K=1024 -> 32)

    // ---- prologue: half-steps 0..3 in flight ----
#pragma unroll
    for (int hh = 0; hh < 4; ++hh) {
        const int hb = (hh & 2) ? BUFSZ : 0;
        const int kc = hh & 1;
#pragma unroll
        for (int i = 0; i < HL; ++i)
            g2lds16(sp[i] + hh * 32, &sS[hb + d0[i] + kc * dk[i]]);
    }

    for (int h = 0; h < NH; ++h) {
        if      (h + 3 < NH) s_wait_vmcnt<3 * HL>();
        else if (h + 2 < NH) s_wait_vmcnt<2 * HL>();
        else if (h + 1 < NH) s_wait_vmcnt<1 * HL>();
        else                 s_wait_vmcnt<0>();
        s_bar();

        const int hb = (h & 2) ? BUFSZ : 0;
        const int kc = h & 1;
        const unsigned short* bufA = &sS[hb + kc * (MR * 512)];
        const unsigned short* bufB = &sS[hb + 2 * MR * 512 + kc * (NC * 512)];

        bf16x8 aF[AM], bF[NCW];
#pragma unroll
        for (int mt = 0; mt < AM; ++mt)
            aF[mt] = *(const bf16x8*)&bufA[(wm * AM + mt) * 512 + lane * 8];
#pragma unroll
        for (int n2 = 0; n2 < NCW; ++n2)
            bF[n2] = *(const bf16x8*)&bufB[(wn * NCW + n2) * 512 + lane * 8];

        __builtin_amdgcn_s_setprio(1);
#pragma unroll
        for (int mt = 0; mt < AM; ++mt)
#pragma unroll
            for (int n2 = 0; n2 < NCW; ++n2)
                acc[mt][n2] = __builtin_amdgcn_mfma_f32_16x16x32_bf16(
                    aF[mt], bF[n2], acc[mt][n2], 0, 0, 0);
        __builtin_amdgcn_s_setprio(0);

        // this wave's ds_reads of region h must be COMPLETE before anyone
        // overwrites it with half-step h+4's loads
        s_wait_lgkm0();
        s_bar();

        if (h + 4 < NH) {
            // h+4 keeps bits 0/1 of h: same buffer, same kc region (just freed)
#pragma unroll
            for (int i = 0; i < HL; ++i)
                g2lds16(sp[i] + (h + 4) * 32, &sS[hb + d0[i] + kc * dk[i]]);
        }
    }

    float bcol[NCW], brow[AM][4];
    if (!p.biasByRow) {
#pragma unroll
        for (int n2 = 0; n2 < NCW; ++n2)
            bcol[n2] = p.bias[col0 + (wn * NCW + n2) * 16 + ln];
    } else {
#pragma unroll
        for (int mt = 0; mt < AM; ++mt)
#pragma unroll
            for (int r = 0; r < 4; ++r)
                brow[mt][r] = p.bias[row0 + wm * (AM * 16) + mt * 16 + qg * 4 + r];
    }

#pragma unroll
    for (int mt = 0; mt < AM; ++mt)
#pragma unroll
        for (int n2 = 0; n2 < NCW; ++n2)
#pragma unroll
            for (int r = 0; r < 4; ++r) {
                int row = row0 + wm * (AM * 16) + mt * 16 + qg * 4 + r;
                int col = col0 + (wn * NCW + n2) * 16 + ln;
                float bb = p.biasByRow ? brow[mt][r] : bcol[n2];
                store_out(&C[(size_t)row * N + col], (acc[mt][n2][r] + bb) * p.scale);
            }
}

// ---------------------------------------------------------------------------
// Flash attention (round-10 structure, unchanged): swapped QK^T, lane-local
// softmax, in-register P exchange; no sP, LDS 40 KB.
// ---------------------------------------------------------------------------
#define BR 64
#define BC 64

__global__ __launch_bounds__(256) void attn_mfma_kernel(
    const unsigned short* __restrict__ Qg, const unsigned short* __restrict__ Kg,
    const unsigned short* __restrict__ VT, unsigned short* __restrict__ O)
{
    __shared__ unsigned short sK[2][8 * 512];   // 16 KB
    __shared__ unsigned short sV[2][8 * 512];   // 16 KB
    __shared__ unsigned short sQ[8 * 512];      // 8 KB

    const int t    = threadIdx.x;
    const int w    = t >> 6;
    const int lane = t & 63;
    const int ln   = lane & 15;
    const int qg   = lane >> 4;

    const int id  = blockIdx.x;
    const int bh  = id & 31;
    const int qt  = (SEQ / BR - 1) - (id >> 5);   // heavy tiles first
    const int b   = bh >> 4;
    const int h   = bh & 15;
    const int qi0 = qt * BR;

    const size_t rowbase = (size_t)b * SEQ;
    const size_t colbase = (size_t)h * DK;

    // ---- stage Q + K/V tile 0 (buf 0) ----
#pragma unroll
    for (int i = 0; i < 2; ++i) {
        const int s = w * 2 + i;
        const int nt = s >> 1, kc = s & 1;
        g2lds16(Qg + (rowbase + qi0 + w * 16 + ln) * DMODEL + colbase + i * 32 + qg * 8,
                &sQ[s * 512]);
        g2lds16(Kg + (rowbase + nt * 16 + ln) * DMODEL + colbase + kc * 32 + qg * 8,
                &sK[0][s * 512]);
        g2lds16(VT + (size_t)(colbase + nt * 16 + ln) * MTOK + rowbase + kc * 32 + qg * 8,
                &sV[0][s * 512]);
    }
    __syncthreads();

    // Q as B-fragment: lane holds Q[q=w*16+ln][d=kc*32+qg*8+j]
    bf16x8 aq[2];
#pragma unroll
    for (int kc = 0; kc < 2; ++kc)
        aq[kc] = *(const bf16x8*)&sQ[(w * 2 + kc) * 512 + lane * 8];

    f32x4 ofrag[4];
#pragma unroll
    for (int nt = 0; nt < 4; ++nt) ofrag[nt] = (f32x4){0.f, 0.f, 0.f, 0.f};
    float osum_p = 0.f;          // per-lane partial denom (own k-slice of q=ln)
    float m_run  = -3.0e38f;     // per-lane running max for q=ln

    // bpermute source lanes for the P-fragment exchange
    const int laneA = ((2 * qg) & 3) * 16 + ln;
    const int laneB = ((2 * qg + 1) & 3) * 16 + ln;
    const bool hiSel = (qg >> 1) & 1;

    const int ntiles = qt + 1;
    for (int jt = 0; jt < ntiles; ++jt) {
        const int cur = jt & 1;

        // ---- prefetch tile jt+1 into the alternate buffer ----
        if (jt + 1 < ntiles) {
            const int j1 = (jt + 1) * BC;
            const int nb = cur ^ 1;
#pragma unroll
            for (int i = 0; i < 2; ++i) {
                const int s = w * 2 + i;
                const int nt = s >> 1, kc = s & 1;
                g2lds16(Kg + (rowbase + j1 + nt * 16 + ln) * DMODEL + colbase + kc * 32 + qg * 8,
                        &sK[nb][s * 512]);
                g2lds16(VT + (size_t)(colbase + nt * 16 + ln) * MTOK + rowbase + j1 + kc * 32 + qg * 8,
                        &sV[nb][s * 512]);
            }
        }

        // ---- S^T = K Q^T (scores pre-scaled by 0.125*log2e) ----
        // sf[nt][r] = S[q=ln][k=nt*16+qg*4+r]
        f32x4 sf[4];
#pragma unroll
        for (int nt = 0; nt < 4; ++nt) {
            f32x4 a2 = (f32x4){0.f, 0.f, 0.f, 0.f};
#pragma unroll
            for (int kc = 0; kc < 2; ++kc) {
                bf16x8 bk = *(const bf16x8*)&sK[cur][(nt * 2 + kc) * 512 + lane * 8];
                a2 = __builtin_amdgcn_mfma_f32_16x16x32_bf16(bk, aq[kc], a2, 0, 0, 0);
            }
            sf[nt] = a2;
        }

        // ---- causal mask (diagonal tile only): k_local > q_local ----
        if (jt == ntiles - 1) {
            const int qloc = w * 16 + ln;
#pragma unroll
            for (int nt = 0; nt < 4; ++nt)
#pragma unroll
                for (int r = 0; r < 4; ++r)
                    if (nt * 16 + qg * 4 + r > qloc) sf[nt][r] = -1.0e30f;
        }

        // ---- online softmax, q-local: scalar m/alpha per lane ----
        float pmax = sf[0][0];
#pragma unroll
        for (int nt = 0; nt < 4; ++nt)
#pragma unroll
            for (int r = 0; r < 4; ++r) pmax = fmaxf(pmax, sf[nt][r]);
        pmax = fmaxf(pmax, __shfl_xor(pmax, 16));
        pmax = fmaxf(pmax, __shfl_xor(pmax, 32));

        const float mn = fmaxf(m_run, pmax);
        const float al = exp2f(m_run - mn);
        m_run = mn;

        float pv[4][4];
        float lsum = 0.f;
#pragma unroll
        for (int nt = 0; nt < 4; ++nt)
#pragma unroll
            for (int r = 0; r < 4; ++r) {
                float e = exp2f(sf[nt][r] - mn);
                pv[nt][r] = e;
                lsum += e;
            }
        osum_p = osum_p * al + lsum;

        // rescale O accumulator rows (row q = qg*4+r needs alpha from lane q)
        float alr[4];
#pragma unroll
        for (int r = 0; r < 4; ++r) alr[r] = __shfl(al, qg * 4 + r);
#pragma unroll
        for (int nt = 0; nt < 4; ++nt)
#pragma unroll
            for (int r = 0; r < 4; ++r) ofrag[nt][r] *= alr[r];

        // ---- pack P to bf16 pairs, exchange into PV A-fragments ----
        unsigned pk0[2], pk1[2], pk2[2], pk3[2];
#pragma unroll
        for (int rr = 0; rr < 2; ++rr) {
            pk0[rr] = cvt_pk_bf16(pv[0][2 * rr], pv[0][2 * rr + 1]);
            pk1[rr] = cvt_pk_bf16(pv[1][2 * rr], pv[1][2 * rr + 1]);
            pk2[rr] = cvt_pk_bf16(pv[2][2 * rr], pv[2][2 * rr + 1]);
            pk3[rr] = cvt_pk_bf16(pv[3][2 * rr], pv[3][2 * rr + 1]);
        }
        union { bf16x8 v; unsigned u[4]; } ap[2];
        {
            unsigned s0, s1;
            s0 = (unsigned)__shfl((int)pk0[0], laneA); s1 = (unsigned)__shfl((int)pk1[0], laneA);
            ap[0].u[0] = hiSel ? s1 : s0;
            s0 = (unsigned)__shfl((int)pk0[1], laneA); s1 = (unsigned)__shfl((int)pk1[1], laneA);
            ap[0].u[1] = hiSel ? s1 : s0;
            s0 = (unsigned)__shfl((int)pk0[0], laneB); s1 = (unsigned)__shfl((int)pk1[0], laneB);
            ap[0].u[2] = hiSel ? s1 : s0;
            s0 = (unsigned)__shfl((int)pk0[1], laneB); s1 = (unsigned)__shfl((int)pk1[1], laneB);
            ap[0].u[3] = hiSel ? s1 : s0;
            s0 = (unsigned)__shfl((int)pk2[0], laneA); s1 = (unsigned)__shfl((int)pk3[0], laneA);
            ap[1].u[0] = hiSel ? s1 : s0;
            s0 = (unsigned)__shfl((int)pk2[1], laneA); s1 = (unsigned)__shfl((int)pk3[1], laneA);
            ap[1].u[1] = hiSel ? s1 : s0;
            s0 = (unsigned)__shfl((int)pk2[0], laneB); s1 = (unsigned)__shfl((int)pk3[0], laneB);
            ap[1].u[2] = hiSel ? s1 : s0;
            s0 = (unsigned)__shfl((int)pk2[1], laneB); s1 = (unsigned)__shfl((int)pk3[1], laneB);
            ap[1].u[3] = hiSel ? s1 : s0;
        }

        // ---- O += P V ----
#pragma unroll
        for (int nt = 0; nt < 4; ++nt) {
#pragma unroll
            for (int kc = 0; kc < 2; ++kc) {
                bf16x8 bv = *(const bf16x8*)&sV[cur][(nt * 2 + kc) * 512 + lane * 8];
                ofrag[nt] = __builtin_amdgcn_mfma_f32_16x16x32_bf16(ap[kc].v, bv, ofrag[nt], 0, 0, 0);
            }
        }

        __syncthreads();    // publish prefetched tile; protect cur for overwrite
    }

    // ---- epilogue: finish denom across k-slices, normalize, write bf16 ----
    float osum = osum_p + __shfl_xor(osum_p, 16);
    osum += __shfl_xor(osum, 32);
    const float invq = 1.0f / osum;     // lane's q = ln
    float inv[4];
#pragma unroll
    for (int r = 0; r < 4; ++r) inv[r] = __shfl(invq, qg * 4 + r);
#pragma unroll
    for (int nt = 0; nt < 4; ++nt)
#pragma unroll
        for (int r = 0; r < 4; ++r) {
            int gq = qi0 + w * 16 + qg * 4 + r;
            O[(rowbase + gq) * DMODEL + colbase + nt * 16 + ln] =
                f2bf(ofrag[nt][r] * inv[r]);
        }
}

// ---------------------------------------------------------------------------
extern "C" void kernel_launch(void* const* d_in, const int* in_sizes, int n_in,
                              void* d_out, int out_size, void* d_ws, size_t ws_size,
                              hipStream_t stream)
{
    const float* q  = (const float*)d_in[0];
    const float* k  = (const float*)d_in[1];
    const float* v  = (const float*)d_in[2];
    // d_in[3] = mask (int32 tril) — causality applied analytically (j<=i).
    const float* wq = (const float*)d_in[4];
    const float* bq = (const float*)d_in[5];
    const float* wk = (const float*)d_in[6];
    const float* bk = (const float*)d_in[7];
    const float* wv = (const float*)d_in[8];
    const float* bv = (const float*)d_in[9];
    const float* wo = (const float*)d_in[10];
    const float* bo = (const float*)d_in[11];
    float* out = (float*)d_out;

    const size_t mat  = (size_t)MTOK * DMODEL;     // 4M elements
    const size_t wmat = (size_t)DMODEL * DMODEL;   // 1M elements
    unsigned short* Abq = (unsigned short*)d_ws;   // bf16 activations
    unsigned short* Abk = Abq + mat;
    unsigned short* Abv = Abk + mat;
    unsigned short* WtQ = Abv + mat;               // bf16 transposed weights
    unsigned short* WtK = WtQ + wmat;
    unsigned short* WtV = WtK + wmat;
    unsigned short* WtO = WtV + wmat;
    unsigned short* Qb  = WtO + wmat;              // bf16 Q proj (pre-scaled)
    unsigned short* Kb  = Qb + mat;                // bf16 K proj
    unsigned short* VT  = Kb + mat;                // bf16 V proj, TRANSPOSED [D][MTOK]
    unsigned short* CTX = VT + mat;                // bf16 attention output

    cvt3_bf16_kernel<<<dim3((unsigned)(mat / 2048), 1, 3), 256, 0, stream>>>(
        q, k, v, Abq, Abk, Abv, (int)mat);
    wtrans_kernel<<<dim3(32, 32, 4), 256, 0, stream>>>(wq, wk, wv, wo, WtQ, WtK, WtV, WtO);

    // fused projections: z0=Q (pre-scaled by 0.125*log2e), z1=K, z2=V transposed.
    // 256x256 tiles: z0/z1: 16x4 = 64 blocks (ctShift=2); z2 (swapped, C=VT
    // [1024 x 4096]): 4x16 = 64 blocks (ctShift=4). Total 192 (%8==0).
    const float qscale = 0.125f * 1.44269504088896f;
    Gemm3 g;
    g.p[0] = (GemmP){Abq, WtQ, bq, (void*)Qb, DMODEL, DMODEL, 2, 0, qscale};
    g.p[1] = (GemmP){Abk, WtK, bk, (void*)Kb, DMODEL, DMODEL, 2, 0, 1.0f};
    g.p[2] = (GemmP){WtV, Abv, bv, (void*)VT, MTOK,   DMODEL, 4, 1, 1.0f};  // swapped operands
    gemm_lds_kernel<unsigned short, 16, 16><<<dim3(64, 1, 3), 512, 0, stream>>>(g);

    attn_mfma_kernel<<<BATCH * NHEAD * (SEQ / BR), 256, 0, stream>>>(Qb, Kb, VT, CTX);

    // output projection: 128x128 tiles -> 32x8 = 256 blocks
    Gemm3 go;
    go.p[0] = (GemmP){CTX, WtO, bo, (void*)out, DMODEL, DMODEL, 3, 0, 1.0f};
    go.p[1] = go.p[0];
    go.p[2] = go.p[0];
    gemm_lds_kernel<float, 8, 8><<<dim3(256, 1, 1), 512, 0, stream>>>(go);
}